// Round 8
// baseline (952.433 us; speedup 1.0000x reference)
//
#include <hip/hip_runtime.h>

typedef unsigned short u16;
typedef float  f32x4  __attribute__((ext_vector_type(4)));
typedef short  bf16x8 __attribute__((ext_vector_type(8)));
typedef u16    u16x8  __attribute__((ext_vector_type(8)));

#define BROWS 32768
#define KTOT  3584
#define NKT   (KTOT / 64)

static __device__ __forceinline__ u16 f2b(float f) {
    unsigned x = __float_as_uint(f);
    x += 0x7fffu + ((x >> 16) & 1u);        // round-to-nearest-even
    return (u16)(x >> 16);
}
static __device__ __forceinline__ float b2f(u16 u) {
    return __uint_as_float(((unsigned)u) << 16);
}
static __device__ __forceinline__ float sigm(float x) {
    return 1.f / (1.f + __expf(-x));
}
static __device__ __forceinline__ float tanh_s(float x) {
    float ax = fabsf(x);
    float e  = __expf(-2.f * ax);
    float t  = (1.f - e) / (1.f + e);
    return copysignf(t, x);
}
static __device__ __forceinline__ void gld16(const u16* g, u16* l) {
    __builtin_amdgcn_global_load_lds(
        (const __attribute__((address_space(1))) void*)g,
        (__attribute__((address_space(3))) void*)l, 16, 0, 0);
}

// ---------------------------------------------------------------------------
// pack_x: Xcat[b] = [bf16(emb[y[b]]) | bf16(s[b]) | bf16(c[b])]   (B x 3584)
// ---------------------------------------------------------------------------
__global__ __launch_bounds__(256) void pack_x(
    const float* __restrict__ s, const int* __restrict__ y,
    const float* __restrict__ c, const float* __restrict__ emb,
    u16* __restrict__ X)
{
    long tid = (long)blockIdx.x * 256 + threadIdx.x;   // B*448 threads
    int  row = (int)(tid / 448);
    int  seg = (int)(tid % 448);
    int  e0  = seg * 8;
    const float* src;
    if (e0 < 512)        src = emb + (long)y[row] * 512 + e0;
    else if (e0 < 1536)  src = s   + (long)row * 1024 + (e0 - 512);
    else                 src = c   + (long)row * 2048 + (e0 - 1536);
    f32x4 a = *(const f32x4*)src;
    f32x4 b = *(const f32x4*)(src + 4);
    u16x8 o;
    o[0]=f2b(a[0]); o[1]=f2b(a[1]); o[2]=f2b(a[2]); o[3]=f2b(a[3]);
    o[4]=f2b(b[0]); o[5]=f2b(b[1]); o[6]=f2b(b[2]); o[7]=f2b(b[3]);
    *(u16x8*)&X[(long)row * KTOT + e0] = o;
}

// ---------------------------------------------------------------------------
// wtrans_all: all 9 weight transposes in one launch.
// dst[n*KTOT + k] = bf16(src[k*1024 + n]).
// ---------------------------------------------------------------------------
__global__ __launch_bounds__(256) void wtrans_all(
    const float* __restrict__ Wz, const float* __restrict__ Uz,
    const float* __restrict__ Cz, const float* __restrict__ Wr,
    const float* __restrict__ Ur, const float* __restrict__ Cr,
    const float* __restrict__ W,  const float* __restrict__ U,
    const float* __restrict__ C,
    u16* __restrict__ WzrT, u16* __restrict__ W2T)
{
    __shared__ float t[32][33];
    int z = blockIdx.z;
    const float* src; u16* dst; int kd;
    switch (z) {
        case 0: src = Wz; dst = WzrT + 0;                  kd = 512;  break;
        case 1: src = Uz; dst = WzrT + 512;                kd = 1024; break;
        case 2: src = Cz; dst = WzrT + 1536;               kd = 2048; break;
        case 3: src = Wr; dst = WzrT + 1024 * KTOT;        kd = 512;  break;
        case 4: src = Ur; dst = WzrT + 1024 * KTOT + 512;  kd = 1024; break;
        case 5: src = Cr; dst = WzrT + 1024 * KTOT + 1536; kd = 2048; break;
        case 6: src = W;  dst = W2T + 0;                   kd = 512;  break;
        case 7: src = U;  dst = W2T + 512;                 kd = 1024; break;
        default: src = C; dst = W2T + 1536;                kd = 2048; break;
    }
    int k0 = blockIdx.x * 32;
    if (k0 >= kd) return;
    int n0 = blockIdx.y * 32;
    int tx = threadIdx.x, ty = threadIdx.y;
    #pragma unroll
    for (int r = ty; r < 32; r += 8)
        t[r][tx] = src[(long)(k0 + r) * 1024 + n0 + tx];
    __syncthreads();
    #pragma unroll
    for (int r = ty; r < 32; r += 8)
        dst[(long)(n0 + r) * KTOT + k0 + tx] = f2b(t[tx][r]);
}

// ---------------------------------------------------------------------------
// 256x256x64 8-wave 4-phase GEMM, quadrant-pipelined ds_reads, with
// pointer-increment staging (minimal per-iteration VALU) and x2-unrolled
// K-loop (compile-time buffer parity). Schedule/gates identical to round 7:
// stageB@P2-top, stageA@P3-top, vmcnt(8) gate at P3 retires exactly tile kt+1.
// ---------------------------------------------------------------------------

#define RDA(P,m,ks)  a[m][ks]  = *(const bf16x8*)((P) + (m)*1024 + (ks)*512 + lane_off)
#define RDB(P,n,ks)  bb[n][ks] = *(const bf16x8*)((P) + (n)*1024 + (ks)*512 + lane_off)
#define RDA4(P,m0)   RDA(P,m0,0);RDA(P,m0,1);RDA(P,m0+1,0);RDA(P,m0+1,1);RDA(P,m0+2,0);RDA(P,m0+2,1);RDA(P,m0+3,0);RDA(P,m0+3,1)
#define RDB2(P,n0)   RDB(P,n0,0);RDB(P,n0,1);RDB(P,n0+1,0);RDB(P,n0+1,1)
#define MM1(m,n,ks) acc[m][n] = __builtin_amdgcn_mfma_f32_16x16x32_bf16(a[m][ks], bb[n][ks], acc[m][n], 0, 0, 0)
#define MMROW(m,n0) MM1(m,n0,0); MM1(m,n0,1); MM1(m,n0+1,0); MM1(m,n0+1,1)
#define MMQUAD(m0,n0) MMROW(m0,n0); MMROW(m0+1,n0); MMROW(m0+2,n0); MMROW(m0+3,n0)

#define PH_MID \
    __builtin_amdgcn_s_barrier(); \
    asm volatile("s_waitcnt lgkmcnt(0)" ::: "memory"); \
    __builtin_amdgcn_sched_barrier(0); \
    __builtin_amdgcn_s_setprio(1);

#define PH_END \
    __builtin_amdgcn_s_setprio(0); \
    __builtin_amdgcn_sched_barrier(0); \
    __builtin_amdgcn_s_barrier();

// stage next A/B tile into buffer at u16-offset BUF (0 or 32768); advances ptrs
#define STAGE_A(BUF) \
    gld16(aP00, smem + (BUF) + ldsA0); aP00 += 64; \
    gld16(aP01, smem + (BUF) + ldsA1); aP01 += 64; \
    gld16(aP10, smem + (BUF) + ldsA2); aP10 += 64; \
    gld16(aP11, smem + (BUF) + ldsA3); aP11 += 64;
#define STAGE_B(BUF) \
    gld16(bP00, smem + (BUF) + ldsB0); bP00 += 64; \
    gld16(bP01, smem + (BUF) + ldsB1); bP01 += 64; \
    gld16(bP10, smem + (BUF) + ldsB2); bP10 += 64; \
    gld16(bP11, smem + (BUF) + ldsB3); bP11 += 64;

template<int MODE>
__global__ __launch_bounds__(512, 1) void gemm8(
    const u16* __restrict__ Xc, const u16* __restrict__ rsin,
    const u16* __restrict__ Wt,
    u16* __restrict__ zb, u16* __restrict__ rsb,
    const u16* __restrict__ zread, float* __restrict__ out, int NT)
{
    extern __shared__ u16 smem[];   // 2 x 32768 u16 = 128 KiB

    int bid = blockIdx.x, nwg = gridDim.x;
    int q   = nwg >> 3;                        // nwg divisible by 8
    int wg  = (bid & 7) * q + (bid >> 3);      // XCD-contiguous swizzle
    int bm  = wg / NT, bn = wg % NT;
    int R0  = bm * 256;
    int C0  = bn * 256;

    int t = threadIdx.x, w = t >> 6, l = t & 63;
    int wr = w >> 2, wc = w & 3;               // 2 x 4 wave grid

    // ---- staging constants (inverse-swizzled global source) ----
    int rl   = l >> 2;                               // subtile row 0..15
    int ccl  = ((l & 3) * 8) ^ ((l >> 5) * 16);      // subtile col (elements)
    int sr0  = w >> 1, sc = w & 1;
    int colb = sc * 32 + ccl;
    int rowA0 = (sr0 + 0) * 16 + rl,  rowA1 = (sr0 + 4) * 16 + rl;  // h=0: i=0,1
    // global source pointers (advance +64 per staged tile)
    const u16* aP00 = Xc + (long)(R0 + rowA0)       * KTOT + colb;
    const u16* aP01 = Xc + (long)(R0 + rowA1)       * KTOT + colb;
    const u16* aP10 = Xc + (long)(R0 + 128 + rowA0) * KTOT + colb;
    const u16* aP11 = Xc + (long)(R0 + 128 + rowA1) * KTOT + colb;
    const u16* bP00 = Wt + (long)(C0 + rowA0)       * KTOT + colb;
    const u16* bP01 = Wt + (long)(C0 + rowA1)       * KTOT + colb;
    const u16* bP10 = Wt + (long)(C0 + 128 + rowA0) * KTOT + colb;
    const u16* bP11 = Wt + (long)(C0 + 128 + rowA1) * KTOT + colb;
    // LDS dest offsets (u16 units, wave-uniform)
    int ldsA0 = (w + 0) * 512,          ldsA1 = (w + 8) * 512;
    int ldsA2 = 8192 + (w + 0) * 512,   ldsA3 = 8192 + (w + 8) * 512;
    int ldsB0 = 16384 + ldsA0, ldsB1 = 16384 + ldsA1;
    int ldsB2 = 16384 + ldsA2, ldsB3 = 16384 + ldsA3;

    // ---- read-side swizzled lane offset (u16 units) ----
    int lane_off = (l & 15) * 32 + (((l >> 4) * 8) ^ (((l >> 3) & 1) * 16));

    f32x4 acc[8][4];
    #pragma unroll
    for (int m = 0; m < 8; m++)
        #pragma unroll
        for (int n = 0; n < 4; n++)
            acc[m][n] = (f32x4){0.f, 0.f, 0.f, 0.f};

    bf16x8 a[8][2], bb[4][2];

    int aoff = wr * 8192;
    int boff = 16384 + (wc >> 1) * 8192 + (wc & 1) * 4096;
    const u16* Ae = smem + aoff;            // buffer0 read bases
    const u16* Be = smem + boff;
    const u16* Ao = Ae + 32768;             // buffer1
    const u16* Bo = Be + 32768;

    // ---- prologue: stage tiles 0,1; certify T0; preload Q0 regs ----
    STAGE_A(0); STAGE_B(0);
    STAGE_A(32768); STAGE_B(32768);
    asm volatile("s_waitcnt vmcnt(8)" ::: "memory");   // tile 0 landed
    __builtin_amdgcn_s_barrier();
    RDA4(Ae, 0); RDB2(Be, 0);

    #pragma unroll 1
    for (int it = 0; it < NKT / 2 - 1; ++it) {          // kt = 2it, 2it+1
        // ======== even K-tile (buffer0) ========
        PH_MID; MMQUAD(0, 0); RDB2(Be, 2); PH_END;
        PH_MID; MMQUAD(0, 2); RDA4(Ae, 4); PH_END;
        STAGE_B(0);                                     // tile 2it+2 (even)
        PH_MID; MMQUAD(4, 2); PH_END;
        if (MODE == 1) {                                // rs-region base switch
            int kt2 = 2 * it + 2;
            if (kt2 == 8) {
                aP00 = rsin + (long)(R0 + rowA0)       * 1024 + colb;
                aP01 = rsin + (long)(R0 + rowA1)       * 1024 + colb;
                aP10 = rsin + (long)(R0 + 128 + rowA0) * 1024 + colb;
                aP11 = rsin + (long)(R0 + 128 + rowA1) * 1024 + colb;
            } else if (kt2 == 24) {
                aP00 = Xc + (long)(R0 + rowA0)       * KTOT + colb + 1536;
                aP01 = Xc + (long)(R0 + rowA1)       * KTOT + colb + 1536;
                aP10 = Xc + (long)(R0 + 128 + rowA0) * KTOT + colb + 1536;
                aP11 = Xc + (long)(R0 + 128 + rowA1) * KTOT + colb + 1536;
            }
        }
        STAGE_A(0);
        asm volatile("s_waitcnt vmcnt(8)" ::: "memory");  // tile 2it+1 landed
        PH_MID; MMQUAD(4, 0); RDA4(Ao, 0); RDB2(Bo, 0); PH_END;
        // ======== odd K-tile (buffer1) ========
        PH_MID; MMQUAD(0, 0); RDB2(Bo, 2); PH_END;
        PH_MID; MMQUAD(0, 2); RDA4(Ao, 4); PH_END;
        STAGE_B(32768);                                 // tile 2it+3 (odd)
        PH_MID; MMQUAD(4, 2); PH_END;
        STAGE_A(32768);
        asm volatile("s_waitcnt vmcnt(8)" ::: "memory");  // tile 2it+2 landed
        PH_MID; MMQUAD(4, 0); RDA4(Ae, 0); RDB2(Be, 0); PH_END;
    }

    // ---- tail: kt = 54 (buffer0), 55 (buffer1); no staging ----
    PH_MID; MMQUAD(0, 0); RDB2(Be, 2); PH_END;
    PH_MID; MMQUAD(0, 2); RDA4(Ae, 4); PH_END;
    PH_MID; MMQUAD(4, 2); PH_END;
    asm volatile("s_waitcnt vmcnt(0)" ::: "memory");      // tile 55 landed
    PH_MID; MMQUAD(4, 0); RDA4(Ao, 0); RDB2(Bo, 0); PH_END;
    PH_MID; MMQUAD(0, 0); RDB2(Bo, 2); PH_END;
    PH_MID; MMQUAD(0, 2); RDA4(Ao, 4); PH_END;
    PH_MID; MMQUAD(4, 2); PH_END;
    PH_MID; MMQUAD(4, 0); PH_END;

    // ---- epilogue: C/D layout col=lane&15, row=(lane>>4)*4+j ----
    // s (prev state) read as bf16 from Xcat cols [512,1536)
    int lr = (l >> 4) * 4, lc = l & 15;
    long R0w = R0 + wr * 128;
    int  C0w = C0 + wc * 64;
    if (MODE == 0) {
        if (C0 < 1024) {                       // whole tile in z region
            #pragma unroll
            for (int m = 0; m < 8; m++)
                #pragma unroll
                for (int n = 0; n < 4; n++) {
                    int col = C0w + n * 16 + lc;
                    #pragma unroll
                    for (int j = 0; j < 4; j++) {
                        long r = R0w + m * 16 + lr + j;
                        zb[r * 1024 + col] = f2b(sigm(acc[m][n][j]));
                    }
                }
        } else {                               // whole tile in r region
            #pragma unroll
            for (int m = 0; m < 8; m++)
                #pragma unroll
                for (int n = 0; n < 4; n++) {
                    int h = C0w + n * 16 + lc - 1024;
                    #pragma unroll
                    for (int j = 0; j < 4; j++) {
                        long r = R0w + m * 16 + lr + j;
                        float sv = b2f(Xc[r * KTOT + 512 + h]);
                        float rr = sigm(acc[m][n][j]);
                        rsb[r * 1024 + h] = f2b(rr * sv);
                    }
                }
        }
    } else {
        #pragma unroll
        for (int m = 0; m < 8; m++)
            #pragma unroll
            for (int n = 0; n < 4; n++) {
                int col = C0w + n * 16 + lc;
                #pragma unroll
                for (int j = 0; j < 4; j++) {
                    long r = R0w + m * 16 + lr + j;
                    float st = tanh_s(acc[m][n][j]);
                    float z  = b2f(zread[r * 1024 + col]);
                    float sv = b2f(Xc[r * KTOT + 512 + col]);
                    out[r * 1024 + col] = fmaf(z, st - sv, sv);
                }
            }
    }
}

// ---------------------------------------------------------------------------
extern "C" void kernel_launch(void* const* d_in, const int* in_sizes, int n_in,
                              void* d_out, int out_size, void* d_ws, size_t ws_size,
                              hipStream_t stream)
{
    const float* s   = (const float*)d_in[0];
    const int*   y   = (const int*)  d_in[1];
    const float* c   = (const float*)d_in[2];
    const float* emb = (const float*)d_in[3];
    const float* Wz  = (const float*)d_in[4];
    const float* Uz  = (const float*)d_in[5];
    const float* Cz  = (const float*)d_in[6];
    const float* Wr  = (const float*)d_in[7];
    const float* Ur  = (const float*)d_in[8];
    const float* Cr  = (const float*)d_in[9];
    const float* W   = (const float*)d_in[10];
    const float* U   = (const float*)d_in[11];
    const float* C   = (const float*)d_in[12];
    float* out = (float*)d_out;

    char* ws = (char*)d_ws;
    u16* Xcat = (u16*)(ws);                                  // B*3584*2
    u16* rsb  = (u16*)(ws + 234881024);                      // B*1024*2
    u16* zbuf = (u16*)(ws + 301989888);                      // B*1024*2
    u16* WzrT = (u16*)(ws + 369098752);                      // 2048*3584*2
    u16* W2T  = (u16*)(ws + 383778816);                      // 1024*3584*2

    hipFuncSetAttribute((const void*)gemm8<0>,
                        hipFuncAttributeMaxDynamicSharedMemorySize, 131072);
    hipFuncSetAttribute((const void*)gemm8<1>,
                        hipFuncAttributeMaxDynamicSharedMemorySize, 131072);

    pack_x<<<BROWS * 448 / 256, 256, 0, stream>>>(s, y, c, emb, Xcat);

    dim3 tb(32, 8);
    wtrans_all<<<dim3(64, 32, 9), tb, 0, stream>>>(
        Wz, Uz, Cz, Wr, Ur, Cr, W, U, C, WzrT, W2T);

    // GEMM1: (B x 3584) @ (3584 x 2048) -> z, rs   (128 x 8 = 1024 wgs)
    gemm8<0><<<(BROWS / 256) * (2048 / 256), 512, 131072, stream>>>(
        Xcat, nullptr, WzrT, zbuf, rsb, nullptr, nullptr, 2048 / 256);

    // GEMM2: ([y|rs|c] B x 3584) @ (3584 x 1024) -> out   (128 x 4 = 512 wgs)
    gemm8<1><<<(BROWS / 256) * (1024 / 256), 512, 131072, stream>>>(
        Xcat, rsb, W2T, nullptr, nullptr, zbuf, out, 1024 / 256);
}

// Round 9
// 863.230 us; speedup vs baseline: 1.1033x; 1.1033x over previous
//
#include <hip/hip_runtime.h>

typedef unsigned short u16;
typedef float  f32x4   __attribute__((ext_vector_type(4)));
typedef float  f32x16  __attribute__((ext_vector_type(16)));
typedef short  bf16x8  __attribute__((ext_vector_type(8)));
typedef u16    u16x8   __attribute__((ext_vector_type(8)));

#define BROWS 32768
#define KTOT  3584
#define NKT   (KTOT / 64)

static __device__ __forceinline__ u16 f2b(float f) {
    unsigned x = __float_as_uint(f);
    x += 0x7fffu + ((x >> 16) & 1u);        // round-to-nearest-even
    return (u16)(x >> 16);
}
static __device__ __forceinline__ float b2f(u16 u) {
    return __uint_as_float(((unsigned)u) << 16);
}
static __device__ __forceinline__ float sigm(float x) {
    return 1.f / (1.f + __expf(-x));
}
static __device__ __forceinline__ float tanh_s(float x) {
    float ax = fabsf(x);
    float e  = __expf(-2.f * ax);
    float t  = (1.f - e) / (1.f + e);
    return copysignf(t, x);
}
static __device__ __forceinline__ void gld16(const u16* g, u16* l) {
    __builtin_amdgcn_global_load_lds(
        (const __attribute__((address_space(1))) void*)g,
        (__attribute__((address_space(3))) void*)l, 16, 0, 0);
}

// ---------------------------------------------------------------------------
// pack_x: Xcat[b] = [bf16(emb[y[b]]) | bf16(s[b]) | bf16(c[b])]   (B x 3584)
// ---------------------------------------------------------------------------
__global__ __launch_bounds__(256) void pack_x(
    const float* __restrict__ s, const int* __restrict__ y,
    const float* __restrict__ c, const float* __restrict__ emb,
    u16* __restrict__ X)
{
    long tid = (long)blockIdx.x * 256 + threadIdx.x;   // B*448 threads
    int  row = (int)(tid / 448);
    int  seg = (int)(tid % 448);
    int  e0  = seg * 8;
    const float* src;
    if (e0 < 512)        src = emb + (long)y[row] * 512 + e0;
    else if (e0 < 1536)  src = s   + (long)row * 1024 + (e0 - 512);
    else                 src = c   + (long)row * 2048 + (e0 - 1536);
    f32x4 a = *(const f32x4*)src;
    f32x4 b = *(const f32x4*)(src + 4);
    u16x8 o;
    o[0]=f2b(a[0]); o[1]=f2b(a[1]); o[2]=f2b(a[2]); o[3]=f2b(a[3]);
    o[4]=f2b(b[0]); o[5]=f2b(b[1]); o[6]=f2b(b[2]); o[7]=f2b(b[3]);
    *(u16x8*)&X[(long)row * KTOT + e0] = o;
}

// ---------------------------------------------------------------------------
// wtrans_all: all 9 weight transposes in one launch.
// dst[n*KTOT + k] = bf16(src[k*1024 + n]).
// ---------------------------------------------------------------------------
__global__ __launch_bounds__(256) void wtrans_all(
    const float* __restrict__ Wz, const float* __restrict__ Uz,
    const float* __restrict__ Cz, const float* __restrict__ Wr,
    const float* __restrict__ Ur, const float* __restrict__ Cr,
    const float* __restrict__ W,  const float* __restrict__ U,
    const float* __restrict__ C,
    u16* __restrict__ WzrT, u16* __restrict__ W2T)
{
    __shared__ float t[32][33];
    int z = blockIdx.z;
    const float* src; u16* dst; int kd;
    switch (z) {
        case 0: src = Wz; dst = WzrT + 0;                  kd = 512;  break;
        case 1: src = Uz; dst = WzrT + 512;                kd = 1024; break;
        case 2: src = Cz; dst = WzrT + 1536;               kd = 2048; break;
        case 3: src = Wr; dst = WzrT + 1024 * KTOT;        kd = 512;  break;
        case 4: src = Ur; dst = WzrT + 1024 * KTOT + 512;  kd = 1024; break;
        case 5: src = Cr; dst = WzrT + 1024 * KTOT + 1536; kd = 2048; break;
        case 6: src = W;  dst = W2T + 0;                   kd = 512;  break;
        case 7: src = U;  dst = W2T + 512;                 kd = 1024; break;
        default: src = C; dst = W2T + 1536;                kd = 2048; break;
    }
    int k0 = blockIdx.x * 32;
    if (k0 >= kd) return;
    int n0 = blockIdx.y * 32;
    int tx = threadIdx.x, ty = threadIdx.y;
    #pragma unroll
    for (int r = ty; r < 32; r += 8)
        t[r][tx] = src[(long)(k0 + r) * 1024 + n0 + tx];
    __syncthreads();
    #pragma unroll
    for (int r = ty; r < 32; r += 8)
        dst[(long)(n0 + r) * KTOT + k0 + tx] = f2b(t[tx][r]);
}

// ---------------------------------------------------------------------------
// 256x256x64 8-wave 4-phase GEMM, round-7 schedule, 32x32x16 MFMA core.
// Per wave: 4 mt (32-row) x 2 nt (32-col) accumulator tiles, f32x16 each.
// Fragment read (st_16x32-swizzled LDS): lane l, tile mt, K-slice ks(0..3):
//   idx = mt*2048 + (ks>>1)*512 + (laneO ^ ((ks&1)*16))
//   laneO = ((l>>4)&1)*1024 + (l&15)*32 + (((l>>5)*8) ^ (((l>>3)&1)*16))
// C/D: col = l&31, row = (reg&3) + 8*(reg>>2) + 4*(l>>5)   [m74/m101]
// Staging/gates identical to round 7 (vmcnt(8) at P3 retires tile kt+1).
// ---------------------------------------------------------------------------

#define RDA32(P,mt,ks) a[mt][ks] = *(const bf16x8*)((P) + (mt)*2048 + ((ks)>>1)*512 + (((ks)&1) ? laneX : laneO))
#define RDB32(P,nt,ks) b[nt][ks] = *(const bf16x8*)((P) + (nt)*2048 + ((ks)>>1)*512 + (((ks)&1) ? laneX : laneO))
#define RDA_T(P,mt) RDA32(P,mt,0); RDA32(P,mt,1); RDA32(P,mt,2); RDA32(P,mt,3)
#define RDB_T(P,nt) RDB32(P,nt,0); RDB32(P,nt,1); RDB32(P,nt,2); RDB32(P,nt,3)
#define MM32(mt,nt,ks) acc[mt][nt] = __builtin_amdgcn_mfma_f32_32x32x16_bf16(a[mt][ks], b[nt][ks], acc[mt][nt], 0, 0, 0)
#define MMQ32(m0,m1,nt) \
    MM32(m0,nt,0); MM32(m1,nt,0); MM32(m0,nt,1); MM32(m1,nt,1); \
    MM32(m0,nt,2); MM32(m1,nt,2); MM32(m0,nt,3); MM32(m1,nt,3)

#define PH_MID \
    __builtin_amdgcn_s_barrier(); \
    asm volatile("s_waitcnt lgkmcnt(0)" ::: "memory"); \
    __builtin_amdgcn_sched_barrier(0); \
    __builtin_amdgcn_s_setprio(1);

#define PH_END \
    __builtin_amdgcn_s_setprio(0); \
    __builtin_amdgcn_sched_barrier(0); \
    __builtin_amdgcn_s_barrier();

template<int MODE>
__global__ __launch_bounds__(512, 1) void gemm8(
    const u16* __restrict__ Xc, const u16* __restrict__ rsin,
    const u16* __restrict__ Wt,
    u16* __restrict__ zb, u16* __restrict__ rsb,
    const u16* __restrict__ zread, float* __restrict__ out, int NT)
{
    extern __shared__ u16 smem[];   // 2 x 32768 u16 = 128 KiB

    int bid = blockIdx.x, nwg = gridDim.x;
    int q   = nwg >> 3;                        // nwg divisible by 8
    int wg  = (bid & 7) * q + (bid >> 3);      // XCD-contiguous swizzle
    int bm  = wg / NT, bn = wg % NT;
    int R0  = bm * 256;
    int C0  = bn * 256;

    int t = threadIdx.x, w = t >> 6, l = t & 63;
    int wr = w >> 2, wc = w & 3;               // 2 x 4 wave grid

    // ---- staging constants (inverse-swizzled global source) ----
    int rl   = l >> 2;                               // subtile row 0..15
    int ccl  = ((l & 3) * 8) ^ ((l >> 5) * 16);      // subtile col (elements)
    int sr0  = w >> 1, sc = w & 1;
    int colb = sc * 32 + ccl;
    int offAx[2][2], offAr[2][2], offB[2][2];
    #pragma unroll
    for (int h = 0; h < 2; h++)
        #pragma unroll
        for (int i = 0; i < 2; i++) {
            int row = h * 128 + (sr0 + i * 4) * 16 + rl;
            offAx[h][i] = (R0 + row) * KTOT + colb;
            offAr[h][i] = (R0 + row) * 1024 + colb - 512;   // rs segment (MODE 1)
            offB [h][i] = (C0 + row) * KTOT + colb;
        }

    auto stageA = [&](int kt) {
        int k0 = kt * 64;
        u16* Ld = smem + (kt & 1) * 32768;
        bool useR = (MODE == 1) && (k0 >= 512) && (k0 < 1536);
        #pragma unroll
        for (int h = 0; h < 2; h++)
            #pragma unroll
            for (int i = 0; i < 2; i++) {
                const u16* g = useR ? (rsin + (offAr[h][i] + k0))
                                    : (Xc   + (offAx[h][i] + k0));
                gld16(g, Ld + h * 8192 + (w + i * 8) * 512);
            }
    };
    auto stageB = [&](int kt) {
        int k0 = kt * 64;
        u16* Ld = smem + (kt & 1) * 32768 + 16384;
        #pragma unroll
        for (int h = 0; h < 2; h++)
            #pragma unroll
            for (int i = 0; i < 2; i++)
                gld16(Wt + (offB[h][i] + k0),
                      Ld + h * 8192 + (w + i * 8) * 512);
    };

    // ---- read-side fragment lane offsets (u16 units) ----
    int laneO = ((l >> 4) & 1) * 1024 + (l & 15) * 32
              + (((l >> 5) * 8) ^ (((l >> 3) & 1) * 16));
    int laneX = laneO ^ 16;

    f32x16 acc[4][2];
    #pragma unroll
    for (int mt = 0; mt < 4; mt++)
        #pragma unroll
        for (int nt = 0; nt < 2; nt++)
            acc[mt][nt] = (f32x16)(0.f);

    bf16x8 a[4][4], b[2][4];

    int aoff = wr * 8192;
    int boff = 16384 + wc * 4096;
    const u16* Ae = smem + aoff;            // buffer0 read bases
    const u16* Be = smem + boff;
    const u16* Ao = Ae + 32768;             // buffer1
    const u16* Bo = Be + 32768;

    // ---- prologue: stage tiles 0,1; certify T0; preload (mt0-1, nt0) ----
    stageA(0); stageB(0);
    stageA(1); stageB(1);
    asm volatile("s_waitcnt vmcnt(8)" ::: "memory");   // tile 0 landed
    __builtin_amdgcn_s_barrier();
    RDA_T(Ae, 0); RDA_T(Ae, 1); RDB_T(Be, 0);

    for (int kt = 0; kt < NKT; ++kt) {
        int bs = kt & 1;
        const u16* Ab = smem + bs * 32768 + aoff;
        const u16* Bb = smem + bs * 32768 + boff;
        const u16* An = smem + (bs ^ 1) * 32768 + aoff;
        const u16* Bn = smem + (bs ^ 1) * 32768 + boff;

        // P0: MFMA (mt0-1 x nt0); pipeline-read nt1
        PH_MID; MMQ32(0, 1, 0); RDB_T(Bb, 1); PH_END;
        // P1: MFMA (mt0-1 x nt1); pipeline-read mt2-3
        PH_MID; MMQ32(0, 1, 1); RDA_T(Ab, 2); RDA_T(Ab, 3); PH_END;
        // P2: stage B(kt+2) (region free since P1-END); MFMA (mt2-3 x nt1)
        if (kt + 2 < NKT) stageB(kt + 2);
        PH_MID; MMQ32(2, 3, 1); PH_END;
        // P3: stage A(kt+2); gate vmcnt(8) = tile kt+1 landed, kt+2 in flight;
        //     MFMA (mt2-3 x nt0); pipeline-read next tile's (mt0-1, nt0)
        if (kt + 2 < NKT) {
            stageA(kt + 2);
            asm volatile("s_waitcnt vmcnt(8)" ::: "memory");
        } else {
            asm volatile("s_waitcnt vmcnt(0)" ::: "memory");
        }
        PH_MID; MMQ32(2, 3, 0);
        if (kt + 1 < NKT) { RDA_T(An, 0); RDA_T(An, 1); RDB_T(Bn, 0); }
        PH_END;
    }

    // ---- epilogue: C/D col = l&31, row = (reg&3) + 8*(reg>>2) + 4*(l>>5) ----
    // s (prev state) read as bf16 from Xcat cols [512,1536)
    int hi4 = (l >> 5) * 4, lc32 = l & 31;
    long R0w = R0 + wr * 128;
    int  C0w = C0 + wc * 64;
    if (MODE == 0) {
        if (C0 < 1024) {                       // whole tile in z region
            #pragma unroll
            for (int mt = 0; mt < 4; mt++)
                #pragma unroll
                for (int nt = 0; nt < 2; nt++) {
                    int col = C0w + nt * 32 + lc32;
                    #pragma unroll
                    for (int qq = 0; qq < 4; qq++)
                        #pragma unroll
                        for (int jj = 0; jj < 4; jj++) {
                            long r = R0w + mt * 32 + qq * 8 + hi4 + jj;
                            zb[r * 1024 + col] = f2b(sigm(acc[mt][nt][qq * 4 + jj]));
                        }
                }
        } else {                               // whole tile in r region
            #pragma unroll
            for (int mt = 0; mt < 4; mt++)
                #pragma unroll
                for (int nt = 0; nt < 2; nt++) {
                    int h = C0w + nt * 32 + lc32 - 1024;
                    #pragma unroll
                    for (int qq = 0; qq < 4; qq++)
                        #pragma unroll
                        for (int jj = 0; jj < 4; jj++) {
                            long r = R0w + mt * 32 + qq * 8 + hi4 + jj;
                            float sv = b2f(Xc[r * KTOT + 512 + h]);
                            float rr = sigm(acc[mt][nt][qq * 4 + jj]);
                            rsb[r * 1024 + h] = f2b(rr * sv);
                        }
                }
        }
    } else {
        #pragma unroll
        for (int mt = 0; mt < 4; mt++)
            #pragma unroll
            for (int nt = 0; nt < 2; nt++) {
                int col = C0w + nt * 32 + lc32;
                #pragma unroll
                for (int qq = 0; qq < 4; qq++)
                    #pragma unroll
                    for (int jj = 0; jj < 4; jj++) {
                        long r = R0w + mt * 32 + qq * 8 + hi4 + jj;
                        float st = tanh_s(acc[mt][nt][qq * 4 + jj]);
                        float z  = b2f(zread[r * 1024 + col]);
                        float sv = b2f(Xc[r * KTOT + 512 + col]);
                        out[r * 1024 + col] = fmaf(z, st - sv, sv);
                    }
            }
    }
}

// ---------------------------------------------------------------------------
extern "C" void kernel_launch(void* const* d_in, const int* in_sizes, int n_in,
                              void* d_out, int out_size, void* d_ws, size_t ws_size,
                              hipStream_t stream)
{
    const float* s   = (const float*)d_in[0];
    const int*   y   = (const int*)  d_in[1];
    const float* c   = (const float*)d_in[2];
    const float* emb = (const float*)d_in[3];
    const float* Wz  = (const float*)d_in[4];
    const float* Uz  = (const float*)d_in[5];
    const float* Cz  = (const float*)d_in[6];
    const float* Wr  = (const float*)d_in[7];
    const float* Ur  = (const float*)d_in[8];
    const float* Cr  = (const float*)d_in[9];
    const float* W   = (const float*)d_in[10];
    const float* U   = (const float*)d_in[11];
    const float* C   = (const float*)d_in[12];
    float* out = (float*)d_out;

    char* ws = (char*)d_ws;
    u16* Xcat = (u16*)(ws);                                  // B*3584*2
    u16* rsb  = (u16*)(ws + 234881024);                      // B*1024*2
    u16* zbuf = (u16*)(ws + 301989888);                      // B*1024*2
    u16* WzrT = (u16*)(ws + 369098752);                      // 2048*3584*2
    u16* W2T  = (u16*)(ws + 383778816);                      // 1024*3584*2

    hipFuncSetAttribute((const void*)gemm8<0>,
                        hipFuncAttributeMaxDynamicSharedMemorySize, 131072);
    hipFuncSetAttribute((const void*)gemm8<1>,
                        hipFuncAttributeMaxDynamicSharedMemorySize, 131072);

    pack_x<<<BROWS * 448 / 256, 256, 0, stream>>>(s, y, c, emb, Xcat);

    dim3 tb(32, 8);
    wtrans_all<<<dim3(64, 32, 9), tb, 0, stream>>>(
        Wz, Uz, Cz, Wr, Ur, Cr, W, U, C, WzrT, W2T);

    // GEMM1: (B x 3584) @ (3584 x 2048) -> z, rs   (128 x 8 = 1024 wgs)
    gemm8<0><<<(BROWS / 256) * (2048 / 256), 512, 131072, stream>>>(
        Xcat, nullptr, WzrT, zbuf, rsb, nullptr, nullptr, 2048 / 256);

    // GEMM2: ([y|rs|c] B x 3584) @ (3584 x 1024) -> out   (128 x 4 = 512 wgs)
    gemm8<1><<<(BROWS / 256) * (1024 / 256), 512, 131072, stream>>>(
        Xcat, rsb, W2T, nullptr, nullptr, zbuf, out, 1024 / 256);
}

// Round 10
// 835.081 us; speedup vs baseline: 1.1405x; 1.0337x over previous
//
#include <hip/hip_runtime.h>

typedef unsigned short u16;
typedef float  f32x4   __attribute__((ext_vector_type(4)));
typedef float  f32x16  __attribute__((ext_vector_type(16)));
typedef short  bf16x8  __attribute__((ext_vector_type(8)));
typedef u16    u16x8   __attribute__((ext_vector_type(8)));

#define BROWS 32768
#define KTOT  3584
#define NKT   (KTOT / 64)

static __device__ __forceinline__ u16 f2b(float f) {
    unsigned x = __float_as_uint(f);
    x += 0x7fffu + ((x >> 16) & 1u);        // round-to-nearest-even
    return (u16)(x >> 16);
}
static __device__ __forceinline__ float b2f(u16 u) {
    return __uint_as_float(((unsigned)u) << 16);
}
static __device__ __forceinline__ float sigm(float x) {
    return 1.f / (1.f + __expf(-x));
}
static __device__ __forceinline__ float tanh_s(float x) {
    float ax = fabsf(x);
    float e  = __expf(-2.f * ax);
    float t  = (1.f - e) / (1.f + e);
    return copysignf(t, x);
}
static __device__ __forceinline__ void gld16(const u16* g, u16* l) {
    __builtin_amdgcn_global_load_lds(
        (const __attribute__((address_space(1))) void*)g,
        (__attribute__((address_space(3))) void*)l, 16, 0, 0);
}

// ---------------------------------------------------------------------------
// pack_x: Xcat[b] = [bf16(emb[y[b]]) | bf16(s[b]) | bf16(c[b])]   (B x 3584)
// ---------------------------------------------------------------------------
__global__ __launch_bounds__(256) void pack_x(
    const float* __restrict__ s, const int* __restrict__ y,
    const float* __restrict__ c, const float* __restrict__ emb,
    u16* __restrict__ X)
{
    long tid = (long)blockIdx.x * 256 + threadIdx.x;   // B*448 threads
    int  row = (int)(tid / 448);
    int  seg = (int)(tid % 448);
    int  e0  = seg * 8;
    const float* src;
    if (e0 < 512)        src = emb + (long)y[row] * 512 + e0;
    else if (e0 < 1536)  src = s   + (long)row * 1024 + (e0 - 512);
    else                 src = c   + (long)row * 2048 + (e0 - 1536);
    f32x4 a = *(const f32x4*)src;
    f32x4 b = *(const f32x4*)(src + 4);
    u16x8 o;
    o[0]=f2b(a[0]); o[1]=f2b(a[1]); o[2]=f2b(a[2]); o[3]=f2b(a[3]);
    o[4]=f2b(b[0]); o[5]=f2b(b[1]); o[6]=f2b(b[2]); o[7]=f2b(b[3]);
    *(u16x8*)&X[(long)row * KTOT + e0] = o;
}

// ---------------------------------------------------------------------------
// wtrans_all: all 9 weight transposes in one launch.
// dst[n*KTOT + k] = bf16(src[k*1024 + n]).
// ---------------------------------------------------------------------------
__global__ __launch_bounds__(256) void wtrans_all(
    const float* __restrict__ Wz, const float* __restrict__ Uz,
    const float* __restrict__ Cz, const float* __restrict__ Wr,
    const float* __restrict__ Ur, const float* __restrict__ Cr,
    const float* __restrict__ W,  const float* __restrict__ U,
    const float* __restrict__ C,
    u16* __restrict__ WzrT, u16* __restrict__ W2T)
{
    __shared__ float t[32][33];
    int z = blockIdx.z;
    const float* src; u16* dst; int kd;
    switch (z) {
        case 0: src = Wz; dst = WzrT + 0;                  kd = 512;  break;
        case 1: src = Uz; dst = WzrT + 512;                kd = 1024; break;
        case 2: src = Cz; dst = WzrT + 1536;               kd = 2048; break;
        case 3: src = Wr; dst = WzrT + 1024 * KTOT;        kd = 512;  break;
        case 4: src = Ur; dst = WzrT + 1024 * KTOT + 512;  kd = 1024; break;
        case 5: src = Cr; dst = WzrT + 1024 * KTOT + 1536; kd = 2048; break;
        case 6: src = W;  dst = W2T + 0;                   kd = 512;  break;
        case 7: src = U;  dst = W2T + 512;                 kd = 1024; break;
        default: src = C; dst = W2T + 1536;                kd = 2048; break;
    }
    int k0 = blockIdx.x * 32;
    if (k0 >= kd) return;
    int n0 = blockIdx.y * 32;
    int tx = threadIdx.x, ty = threadIdx.y;
    #pragma unroll
    for (int r = ty; r < 32; r += 8)
        t[r][tx] = src[(long)(k0 + r) * 1024 + n0 + tx];
    __syncthreads();
    #pragma unroll
    for (int r = ty; r < 32; r += 8)
        dst[(long)(n0 + r) * KTOT + k0 + tx] = f2b(t[tx][r]);
}

// ---------------------------------------------------------------------------
// 256x256x64 8-wave 4-phase GEMM, round-7 schedule, 32x32x16 MFMA core,
// bank-conflict-free 3-bit swizzle:
//   f(row) = ((row>>3)&1)*16  ^  ((row>>4)&1)*8      (u16 col-slot XOR)
// Write side: row bit3 = staging-lane l>>5; row bit4 = (w>>1)&1 (wave-const).
// Read  side: row bit3 = (l>>3)&1;          row bit4 = (l>>4)&1.
// This spreads each 32-lane half-wave across all four bank quads (was
// concentrated in quads {0,2} -> 4-way conflict, 4.4e7 in round 9).
// C/D: col = l&31, row = (reg&3) + 8*(reg>>2) + 4*(l>>5)   [m74/m101]
// Staging/gates identical to round 7 (vmcnt(8) at P3 retires tile kt+1).
// ---------------------------------------------------------------------------

#define RDA32(P,mt,ks) a[mt][ks] = *(const bf16x8*)((P) + (mt)*2048 + ((ks)>>1)*512 + (((ks)&1) ? laneX : laneO))
#define RDB32(P,nt,ks) b[nt][ks] = *(const bf16x8*)((P) + (nt)*2048 + ((ks)>>1)*512 + (((ks)&1) ? laneX : laneO))
#define RDA_T(P,mt) RDA32(P,mt,0); RDA32(P,mt,1); RDA32(P,mt,2); RDA32(P,mt,3)
#define RDB_T(P,nt) RDB32(P,nt,0); RDB32(P,nt,1); RDB32(P,nt,2); RDB32(P,nt,3)
#define MM32(mt,nt,ks) acc[mt][nt] = __builtin_amdgcn_mfma_f32_32x32x16_bf16(a[mt][ks], b[nt][ks], acc[mt][nt], 0, 0, 0)
#define MMQ32(m0,m1,nt) \
    MM32(m0,nt,0); MM32(m1,nt,0); MM32(m0,nt,1); MM32(m1,nt,1); \
    MM32(m0,nt,2); MM32(m1,nt,2); MM32(m0,nt,3); MM32(m1,nt,3)

#define PH_MID \
    __builtin_amdgcn_s_barrier(); \
    asm volatile("s_waitcnt lgkmcnt(0)" ::: "memory"); \
    __builtin_amdgcn_sched_barrier(0); \
    __builtin_amdgcn_s_setprio(1);

#define PH_END \
    __builtin_amdgcn_s_setprio(0); \
    __builtin_amdgcn_sched_barrier(0); \
    __builtin_amdgcn_s_barrier();

template<int MODE>
__global__ __launch_bounds__(512, 1) void gemm8(
    const u16* __restrict__ Xc, const u16* __restrict__ rsin,
    const u16* __restrict__ Wt,
    u16* __restrict__ zb, u16* __restrict__ rsb,
    const u16* __restrict__ zread, float* __restrict__ out, int NT)
{
    extern __shared__ u16 smem[];   // 2 x 32768 u16 = 128 KiB

    int bid = blockIdx.x, nwg = gridDim.x;
    int q   = nwg >> 3;                        // nwg divisible by 8
    int wg  = (bid & 7) * q + (bid >> 3);      // XCD-contiguous swizzle
    int bm  = wg / NT, bn = wg % NT;
    int R0  = bm * 256;
    int C0  = bn * 256;

    int t = threadIdx.x, w = t >> 6, l = t & 63;
    int wr = w >> 2, wc = w & 3;               // 2 x 4 wave grid

    // ---- staging constants (inverse-swizzled global source) ----
    int rl   = l >> 2;                               // subtile row 0..15
    // col slot XOR: row bit3 = (l>>5), row bit4 = (w>>1)&1 (wave-const)
    int ccl  = ((l & 3) * 8) ^ ((l >> 5) * 16) ^ (((w >> 1) & 1) * 8);
    int sr0  = w >> 1, sc = w & 1;
    int colb = sc * 32 + ccl;
    int offAx[2][2], offAr[2][2], offB[2][2];
    #pragma unroll
    for (int h = 0; h < 2; h++)
        #pragma unroll
        for (int i = 0; i < 2; i++) {
            int row = h * 128 + (sr0 + i * 4) * 16 + rl;
            offAx[h][i] = (R0 + row) * KTOT + colb;
            offAr[h][i] = (R0 + row) * 1024 + colb - 512;   // rs segment (MODE 1)
            offB [h][i] = (C0 + row) * KTOT + colb;
        }

    auto stageA = [&](int kt) {
        int k0 = kt * 64;
        u16* Ld = smem + (kt & 1) * 32768;
        bool useR = (MODE == 1) && (k0 >= 512) && (k0 < 1536);
        #pragma unroll
        for (int h = 0; h < 2; h++)
            #pragma unroll
            for (int i = 0; i < 2; i++) {
                const u16* g = useR ? (rsin + (offAr[h][i] + k0))
                                    : (Xc   + (offAx[h][i] + k0));
                gld16(g, Ld + h * 8192 + (w + i * 8) * 512);
            }
    };
    auto stageB = [&](int kt) {
        int k0 = kt * 64;
        u16* Ld = smem + (kt & 1) * 32768 + 16384;
        #pragma unroll
        for (int h = 0; h < 2; h++)
            #pragma unroll
            for (int i = 0; i < 2; i++)
                gld16(Wt + (offB[h][i] + k0),
                      Ld + h * 8192 + (w + i * 8) * 512);
    };

    // ---- read-side fragment lane offsets (u16 units) ----
    int laneO = ((l >> 4) & 1) * 1024 + (l & 15) * 32
              + ((((l >> 5) * 8) ^ (((l >> 3) & 1) * 16)) ^ (((l >> 4) & 1) * 8));
    int laneX = laneO ^ 16;

    f32x16 acc[4][2];
    #pragma unroll
    for (int mt = 0; mt < 4; mt++)
        #pragma unroll
        for (int nt = 0; nt < 2; nt++)
            acc[mt][nt] = (f32x16)(0.f);

    bf16x8 a[4][4], b[2][4];

    int aoff = wr * 8192;
    int boff = 16384 + wc * 4096;
    const u16* Ae = smem + aoff;            // buffer0 read bases
    const u16* Be = smem + boff;
    const u16* Ao = Ae + 32768;             // buffer1
    const u16* Bo = Be + 32768;

    // ---- prologue: stage tiles 0,1; certify T0; preload (mt0-1, nt0) ----
    stageA(0); stageB(0);
    stageA(1); stageB(1);
    asm volatile("s_waitcnt vmcnt(8)" ::: "memory");   // tile 0 landed
    __builtin_amdgcn_s_barrier();
    RDA_T(Ae, 0); RDA_T(Ae, 1); RDB_T(Be, 0);

    for (int kt = 0; kt < NKT; ++kt) {
        int bs = kt & 1;
        const u16* Ab = smem + bs * 32768 + aoff;
        const u16* Bb = smem + bs * 32768 + boff;
        const u16* An = smem + (bs ^ 1) * 32768 + aoff;
        const u16* Bn = smem + (bs ^ 1) * 32768 + boff;

        // P0: MFMA (mt0-1 x nt0); pipeline-read nt1
        PH_MID; MMQ32(0, 1, 0); RDB_T(Bb, 1); PH_END;
        // P1: MFMA (mt0-1 x nt1); pipeline-read mt2-3
        PH_MID; MMQ32(0, 1, 1); RDA_T(Ab, 2); RDA_T(Ab, 3); PH_END;
        // P2: stage B(kt+2) (region free since P1-END); MFMA (mt2-3 x nt1)
        if (kt + 2 < NKT) stageB(kt + 2);
        PH_MID; MMQ32(2, 3, 1); PH_END;
        // P3: stage A(kt+2); gate vmcnt(8) = tile kt+1 landed, kt+2 in flight;
        //     MFMA (mt2-3 x nt0); pipeline-read next tile's (mt0-1, nt0)
        if (kt + 2 < NKT) {
            stageA(kt + 2);
            asm volatile("s_waitcnt vmcnt(8)" ::: "memory");
        } else {
            asm volatile("s_waitcnt vmcnt(0)" ::: "memory");
        }
        PH_MID; MMQ32(2, 3, 0);
        if (kt + 1 < NKT) { RDA_T(An, 0); RDA_T(An, 1); RDB_T(Bn, 0); }
        PH_END;
    }

    // ---- epilogue: C/D col = l&31, row = (reg&3) + 8*(reg>>2) + 4*(l>>5) ----
    // s (prev state) read as bf16 from Xcat cols [512,1536)
    int hi4 = (l >> 5) * 4, lc32 = l & 31;
    long R0w = R0 + wr * 128;
    int  C0w = C0 + wc * 64;
    if (MODE == 0) {
        if (C0 < 1024) {                       // whole tile in z region
            #pragma unroll
            for (int mt = 0; mt < 4; mt++)
                #pragma unroll
                for (int nt = 0; nt < 2; nt++) {
                    int col = C0w + nt * 32 + lc32;
                    #pragma unroll
                    for (int qq = 0; qq < 4; qq++)
                        #pragma unroll
                        for (int jj = 0; jj < 4; jj++) {
                            long r = R0w + mt * 32 + qq * 8 + hi4 + jj;
                            zb[r * 1024 + col] = f2b(sigm(acc[mt][nt][qq * 4 + jj]));
                        }
                }
        } else {                               // whole tile in r region
            #pragma unroll
            for (int mt = 0; mt < 4; mt++)
                #pragma unroll
                for (int nt = 0; nt < 2; nt++) {
                    int h = C0w + nt * 32 + lc32 - 1024;
                    #pragma unroll
                    for (int qq = 0; qq < 4; qq++)
                        #pragma unroll
                        for (int jj = 0; jj < 4; jj++) {
                            long r = R0w + mt * 32 + qq * 8 + hi4 + jj;
                            float sv = b2f(Xc[r * KTOT + 512 + h]);
                            float rr = sigm(acc[mt][nt][qq * 4 + jj]);
                            rsb[r * 1024 + h] = f2b(rr * sv);
                        }
                }
        }
    } else {
        #pragma unroll
        for (int mt = 0; mt < 4; mt++)
            #pragma unroll
            for (int nt = 0; nt < 2; nt++) {
                int col = C0w + nt * 32 + lc32;
                #pragma unroll
                for (int qq = 0; qq < 4; qq++)
                    #pragma unroll
                    for (int jj = 0; jj < 4; jj++) {
                        long r = R0w + mt * 32 + qq * 8 + hi4 + jj;
                        float st = tanh_s(acc[mt][nt][qq * 4 + jj]);
                        float z  = b2f(zread[r * 1024 + col]);
                        float sv = b2f(Xc[r * KTOT + 512 + col]);
                        out[r * 1024 + col] = fmaf(z, st - sv, sv);
                    }
            }
    }
}

// ---------------------------------------------------------------------------
extern "C" void kernel_launch(void* const* d_in, const int* in_sizes, int n_in,
                              void* d_out, int out_size, void* d_ws, size_t ws_size,
                              hipStream_t stream)
{
    const float* s   = (const float*)d_in[0];
    const int*   y   = (const int*)  d_in[1];
    const float* c   = (const float*)d_in[2];
    const float* emb = (const float*)d_in[3];
    const float* Wz  = (const float*)d_in[4];
    const float* Uz  = (const float*)d_in[5];
    const float* Cz  = (const float*)d_in[6];
    const float* Wr  = (const float*)d_in[7];
    const float* Ur  = (const float*)d_in[8];
    const float* Cr  = (const float*)d_in[9];
    const float* W   = (const float*)d_in[10];
    const float* U   = (const float*)d_in[11];
    const float* C   = (const float*)d_in[12];
    float* out = (float*)d_out;

    char* ws = (char*)d_ws;
    u16* Xcat = (u16*)(ws);                                  // B*3584*2
    u16* rsb  = (u16*)(ws + 234881024);                      // B*1024*2
    u16* zbuf = (u16*)(ws + 301989888);                      // B*1024*2
    u16* WzrT = (u16*)(ws + 369098752);                      // 2048*3584*2
    u16* W2T  = (u16*)(ws + 383778816);                      // 1024*3584*2

    hipFuncSetAttribute((const void*)gemm8<0>,
                        hipFuncAttributeMaxDynamicSharedMemorySize, 131072);
    hipFuncSetAttribute((const void*)gemm8<1>,
                        hipFuncAttributeMaxDynamicSharedMemorySize, 131072);

    pack_x<<<BROWS * 448 / 256, 256, 0, stream>>>(s, y, c, emb, Xcat);

    dim3 tb(32, 8);
    wtrans_all<<<dim3(64, 32, 9), tb, 0, stream>>>(
        Wz, Uz, Cz, Wr, Ur, Cr, W, U, C, WzrT, W2T);

    // GEMM1: (B x 3584) @ (3584 x 2048) -> z, rs   (128 x 8 = 1024 wgs)
    gemm8<0><<<(BROWS / 256) * (2048 / 256), 512, 131072, stream>>>(
        Xcat, nullptr, WzrT, zbuf, rsb, nullptr, nullptr, 2048 / 256);

    // GEMM2: ([y|rs|c] B x 3584) @ (3584 x 1024) -> out   (128 x 4 = 512 wgs)
    gemm8<1><<<(BROWS / 256) * (1024 / 256), 512, 131072, stream>>>(
        Xcat, rsb, W2T, nullptr, nullptr, zbuf, out, 1024 / 256);
}